// Round 19
// baseline (381.510 us; speedup 1.0000x reference)
//
#include <hip/hip_runtime.h>
#include <math.h>

typedef __attribute__((ext_vector_type(8))) short short8;
typedef __attribute__((ext_vector_type(4))) short short4v;
typedef __attribute__((ext_vector_type(4))) float f32x4;
typedef unsigned short u16;
typedef unsigned int u32;
typedef unsigned long long u64;

namespace {
constexpr int kB = 4;
constexpr int kL = 4096;
constexpr int kC = 512;
constexpr int kH = 8;
constexpr int kLr = 1024;
constexpr int kCH = 2048;
constexpr int kKred = 3584;
constexpr float kEps = 1e-5f;
}

#if __has_builtin(__builtin_amdgcn_mfma_f32_16x16x16bf16_1k)
#define MFMA16X16(a, b, c) __builtin_amdgcn_mfma_f32_16x16x16bf16_1k((a), (b), (c), 0, 0, 0)
#else
__device__ __forceinline__ f32x4 mfma16_fb(short4v a, short4v b, f32x4 c) {
  asm volatile("v_mfma_f32_16x16x16_bf16 %0, %1, %2, %0\n\ts_nop 7\n\ts_nop 3"
               : "+v"(c) : "v"(a), "v"(b));
  return c;
}
#define MFMA16X16(a, b, c) mfma16_fb((a), (b), (c))
#endif

__device__ __forceinline__ float bf2f(u16 u) { return __uint_as_float(((u32)u) << 16); }
__device__ __forceinline__ u16 f2bf(float f) {
  u32 u = __float_as_uint(f);
  u32 r = (u + 0x7fffu + ((u >> 16) & 1u)) >> 16;
  return (u16)r;
}
__device__ __forceinline__ u32 cvtpk(float lo, float hi) {
  u32 r;
  asm("v_cvt_pk_bf16_f32 %0, %1, %2" : "=v"(r) : "v"(lo), "v"(hi));
  return r;
}
__device__ __forceinline__ float fexp2(float x) {
#if __has_builtin(__builtin_amdgcn_exp2f)
  return __builtin_amdgcn_exp2f(x);
#else
  float r;
  asm("v_exp_f32 %0, %1" : "=v"(r) : "v"(x));
  return r;
#endif
}

__device__ __forceinline__ void gload_lds16(const void* g, void* l) {
  __builtin_amdgcn_global_load_lds(
      (const __attribute__((address_space(1))) unsigned int*)g,
      (__attribute__((address_space(3))) unsigned int*)l, 16, 0, 0);
}

// swizzled frag read: rows of 64 bf16 (128B), XOR (row&7) on 16B slot index
__device__ __forceinline__ short8 ldsfrag(const u16* base, int row, int col16) {
  return *(const short8*)(base + (size_t)(((row << 3) + (col16 ^ (row & 7))) << 3));
}

// ---------------- merged prologue: weight cvt/repack + LN0 ----------------
__global__ __launch_bounds__(256) void prep_ln0_kernel(
    const float* __restrict__ w_q, const float* __restrict__ w_k,
    const float* __restrict__ w_v, const float* __restrict__ w_o,
    const float* __restrict__ w_f1, const float* __restrict__ w_f2,
    u16* __restrict__ dst, const float* __restrict__ w_red, u16* __restrict__ wredb,
    const float* __restrict__ x, u16* __restrict__ h_out,
    const float* __restrict__ gam, const float* __restrict__ bet) {
  const int bid = blockIdx.x;
  const int tid = threadIdx.x;
  if (bid < 2304) {
    const int i = (bid * 256 + tid) * 4;  // total 2,359,296
    const int seg = i >> 18;
    const float* src;
    int off;
    if (seg < 5) {
      src = (seg == 0) ? w_q : (seg == 1) ? w_k : (seg == 2) ? w_v : (seg == 3) ? w_o : w_f1;
      off = i & 262143;
    } else {
      src = w_f2;
      off = i - 1310720;
    }
    const float4 v = *(const float4*)(src + off);
    u16 o[4] = {f2bf(v.x), f2bf(v.y), f2bf(v.z), f2bf(v.w)};
    *(u64*)(dst + i) = *(u64*)o;
    return;
  }
  if (bid < 9472) {
    const int idx = (bid - 2304) * 256 + tid;
    if (idx >= kC * kKred) return;
    const int o = idx / kKred;
    const int rem = idx - o * kKred;
    const int t = rem >> 9;
    const int i = rem & (kC - 1);
    wredb[idx] = f2bf(w_red[(size_t)(o * kC + i) * 7 + t]);
    return;
  }
  // ---- LN0 over row = bid - 9472 ----
  const int row = bid - 9472;
  const float2 v = *(const float2*)(x + (size_t)row * kC + tid * 2);
  float s = v.x + v.y;
  float ss = v.x * v.x + v.y * v.y;
#pragma unroll
  for (int off = 32; off > 0; off >>= 1) {
    s += __shfl_down(s, off);
    ss += __shfl_down(ss, off);
  }
  __shared__ float wsum[4][2];
  __shared__ float mi[2];
  const int wave = tid >> 6, lane = tid & 63;
  if (lane == 0) { wsum[wave][0] = s; wsum[wave][1] = ss; }
  __syncthreads();
  if (tid == 0) {
    const float S = wsum[0][0] + wsum[1][0] + wsum[2][0] + wsum[3][0];
    const float SS = wsum[0][1] + wsum[1][1] + wsum[2][1] + wsum[3][1];
    const float mean = S * (1.0f / kC);
    const float var = SS * (1.0f / kC) - mean * mean;
    mi[0] = mean;
    mi[1] = rsqrtf(var + kEps);
  }
  __syncthreads();
  const float mean = mi[0], inv = mi[1];
  const float2 gg = *(const float2*)(gam + tid * 2);
  const float2 bb = *(const float2*)(bet + tid * 2);
  u16 o2[2] = {f2bf((v.x - mean) * inv * gg.x + bb.x), f2bf((v.y - mean) * inv * gg.y + bb.y)};
  *(u32*)(h_out + (size_t)row * kC + tid * 2) = *(u32*)o2;
}

// ---------------- sum 2 split-K fp32 partials -> LN -> bf16 ----------------
__global__ __launch_bounds__(256) void reduce2_ln_kernel(const float* __restrict__ P,
                                                         u16* __restrict__ out,
                                                         const float* __restrict__ g,
                                                         const float* __restrict__ be) {
  const int row = blockIdx.x;
  const int tid = threadIdx.x;
  const size_t stride = (size_t)kB * kLr * kC;
  float2 v = make_float2(0.f, 0.f);
#pragma unroll
  for (int z = 0; z < 2; ++z) {
    const float2 p = *(const float2*)(P + z * stride + (size_t)row * kC + tid * 2);
    v.x += p.x;
    v.y += p.y;
  }
  float s = v.x + v.y;
  float ss = v.x * v.x + v.y * v.y;
#pragma unroll
  for (int off = 32; off > 0; off >>= 1) {
    s += __shfl_down(s, off);
    ss += __shfl_down(ss, off);
  }
  __shared__ float wsum[4][2];
  __shared__ float mi[2];
  const int wave = tid >> 6, lane = tid & 63;
  if (lane == 0) { wsum[wave][0] = s; wsum[wave][1] = ss; }
  __syncthreads();
  if (tid == 0) {
    const float S = wsum[0][0] + wsum[1][0] + wsum[2][0] + wsum[3][0];
    const float SS = wsum[0][1] + wsum[1][1] + wsum[2][1] + wsum[3][1];
    const float mean = S * (1.0f / kC);
    const float var = SS * (1.0f / kC) - mean * mean;
    mi[0] = mean;
    mi[1] = rsqrtf(var + kEps);
  }
  __syncthreads();
  const float mean = mi[0], inv = mi[1];
  const float2 gg = *(const float2*)(g + tid * 2);
  const float2 bb = *(const float2*)(be + tid * 2);
  u16 o2[2] = {f2bf((v.x - mean) * inv * gg.x + bb.x), f2bf((v.y - mean) * inv * gg.y + bb.y)};
  *(u32*)(out + (size_t)row * kC + tid * 2) = *(u32*)o2;
}

// ---------------- fdw = gelu(dwconv3(f1)); full occupancy elementwise ----------------
__global__ __launch_bounds__(256) void dwgelu_kernel(const u16* __restrict__ f1,
                                                     const float* __restrict__ wdw,
                                                     u16* __restrict__ fdw) {
  const int row = blockIdx.x;
  const int l = row & (kL - 1);
  const int rb = row - l;
  const int cc0 = threadIdx.x * 8;
  const int cg = cc0 >> 2;
  const int lm = (l == 0) ? 1 : l - 1;
  const int lp = (l == kL - 1) ? kL - 2 : l + 1;
  const u32 xm = *(const u32*)(f1 + (size_t)(rb + lm) * kC + cg);
  const u32 x0 = *(const u32*)(f1 + (size_t)(rb + l) * kC + cg);
  const u32 xp = *(const u32*)(f1 + (size_t)(rb + lp) * kC + cg);
  const float xml = bf2f((u16)xm), xmh = bf2f((u16)(xm >> 16));
  const float x0l = bf2f((u16)x0), x0h = bf2f((u16)(x0 >> 16));
  const float xpl = bf2f((u16)xp), xph = bf2f((u16)(xp >> 16));
  float wv[24];
#pragma unroll
  for (int t = 0; t < 6; ++t)
    *(float4*)&wv[t * 4] = *(const float4*)(wdw + (size_t)cc0 * 3 + t * 4);
  short8 pk;
#pragma unroll
  for (int j = 0; j < 8; ++j) {
    const float a_ = (j < 4) ? xml : xmh;
    const float b_ = (j < 4) ? x0l : x0h;
    const float c_ = (j < 4) ? xpl : xph;
    const float dw = wv[j * 3] * a_ + wv[j * 3 + 1] * b_ + wv[j * 3 + 2] * c_;
    pk[j] = (short)f2bf(0.5f * dw * (1.0f + erff(dw * 0.70710678118654752440f)));
  }
  *(short8*)(fdw + (size_t)row * kCH + cc0) = pk;
}

// ---------------- MFMA bf16 GEMM (128x128, splitK, dbuf, 4 waves) for reducer ----------------
__global__ __launch_bounds__(256) void mgemm_red_kernel(
    const u16* __restrict__ A, const u16* __restrict__ W, float* __restrict__ OutF,
    int M, int N, int K) {
  __shared__ __align__(16) u16 As[2][128 * 64];
  __shared__ __align__(16) u16 Bs[2][128 * 64];
  const int tid = threadIdx.x;
  const int lane = tid & 63, w = tid >> 6;
  const int bid = blockIdx.x;
  const int m0 = (bid & 31) << 7, n0 = (bid >> 5) << 7;
  const int wm = (w >> 1) * 64, wn = (w & 1) * 64;
  const f32x4 zero = {0.f, 0.f, 0.f, 0.f};
  f32x4 acc[4][4];
#pragma unroll
  for (int i = 0; i < 4; ++i)
#pragma unroll
    for (int j = 0; j < 4; ++j) acc[i][j] = zero;

  const int kc = K / gridDim.z;
  const int kBeg = blockIdx.z * kc;
  float* outp = OutF + (size_t)blockIdx.z * M * N;

  auto stage = [&](int buf, int k0) {
#pragma unroll
    for (int c = 0; c < 4; ++c) {
      const int ci = w * 4 + c;
      const int idx = ci * 64 + lane;
      const int row = idx >> 3, s = idx & 7;
      const int c16 = s ^ (row & 7);
      gload_lds16(W + (size_t)(n0 + row) * K + k0 + c16 * 8, (char*)Bs[buf] + ci * 1024);
      const int m = m0 + row;
      const int b = m >> 10, lr = m & (kLr - 1);
      const int k = k0 + c16 * 8;
      const int t = k >> 9, i = k & (kC - 1);
      int pos = 4 * lr + t - 3;
      pos = pos < 0 ? -pos : (pos >= kL ? 2 * kL - 2 - pos : pos);
      gload_lds16(A + ((size_t)(b << 12) + pos) * kC + i, (char*)As[buf] + ci * 1024);
    }
  };

  const int nk = kc >> 6;
  stage(0, kBeg);
  __syncthreads();
  for (int t = 0; t < nk; ++t) {
    const int cur = t & 1;
    if (t + 1 < nk) stage(cur ^ 1, kBeg + ((t + 1) << 6));
#pragma unroll
    for (int kst = 0; kst < 2; ++kst) {
      short8 af[4], bfr[4];
      const int c16 = kst * 4 + (lane >> 4);
#pragma unroll
      for (int mb = 0; mb < 4; ++mb) af[mb] = ldsfrag(As[cur], wm + mb * 16 + (lane & 15), c16);
#pragma unroll
      for (int nb = 0; nb < 4; ++nb) bfr[nb] = ldsfrag(Bs[cur], wn + nb * 16 + (lane & 15), c16);
#pragma unroll
      for (int mb = 0; mb < 4; ++mb)
#pragma unroll
        for (int nb = 0; nb < 4; ++nb)
          acc[mb][nb] = __builtin_amdgcn_mfma_f32_16x16x32_bf16(af[mb], bfr[nb], acc[mb][nb], 0, 0, 0);
    }
    __syncthreads();
  }
#pragma unroll
  for (int mb = 0; mb < 4; ++mb)
#pragma unroll
    for (int r = 0; r < 4; ++r) {
      const int row = m0 + wm + mb * 16 + ((lane >> 4) << 2) + r;
#pragma unroll
      for (int nb = 0; nb < 4; ++nb)
        outp[(size_t)row * N + n0 + wn + nb * 16 + (lane & 15)] = acc[mb][nb][r];
    }
}

// ---------------- MFMA bf16 GEMM (128x128, dbuf, 4 waves) + fp32 residual (ffn2) ----------------
__global__ __launch_bounds__(256) void mgemm_res_kernel(
    const u16* __restrict__ A, const u16* __restrict__ W,
    const float* __restrict__ Res, float* __restrict__ OutF, int M, int N, int K) {
  __shared__ __align__(16) u16 As[2][128 * 64];
  __shared__ __align__(16) u16 Bs[2][128 * 64];
  const int tid = threadIdx.x;
  const int lane = tid & 63, w = tid >> 6;
  const int bid = blockIdx.x;
  const int m0 = (bid & 127) << 7, n0 = (bid >> 7) << 7;
  const int wm = (w >> 1) * 64, wn = (w & 1) * 64;
  const f32x4 zero = {0.f, 0.f, 0.f, 0.f};
  f32x4 acc[4][4];
#pragma unroll
  for (int i = 0; i < 4; ++i)
#pragma unroll
    for (int j = 0; j < 4; ++j) acc[i][j] = zero;

  auto stage = [&](int buf, int k0) {
#pragma unroll
    for (int c = 0; c < 4; ++c) {
      const int ci = w * 4 + c;
      const int idx = ci * 64 + lane;
      const int row = idx >> 3, s = idx & 7;
      const int c16 = s ^ (row & 7);
      gload_lds16(W + (size_t)(n0 + row) * K + k0 + c16 * 8, (char*)Bs[buf] + ci * 1024);
      gload_lds16(A + (size_t)(m0 + row) * K + k0 + c16 * 8, (char*)As[buf] + ci * 1024);
    }
  };

  const int nk = K >> 6;
  stage(0, 0);
  __syncthreads();
  for (int t = 0; t < nk; ++t) {
    const int cur = t & 1;
    if (t + 1 < nk) stage(cur ^ 1, (t + 1) << 6);
#pragma unroll
    for (int kst = 0; kst < 2; ++kst) {
      short8 af[4], bfr[4];
      const int c16 = kst * 4 + (lane >> 4);
#pragma unroll
      for (int mb = 0; mb < 4; ++mb) af[mb] = ldsfrag(As[cur], wm + mb * 16 + (lane & 15), c16);
#pragma unroll
      for (int nb = 0; nb < 4; ++nb) bfr[nb] = ldsfrag(Bs[cur], wn + nb * 16 + (lane & 15), c16);
#pragma unroll
      for (int mb = 0; mb < 4; ++mb)
#pragma unroll
        for (int nb = 0; nb < 4; ++nb)
          acc[mb][nb] = __builtin_amdgcn_mfma_f32_16x16x32_bf16(af[mb], bfr[nb], acc[mb][nb], 0, 0, 0);
    }
    __syncthreads();
  }
#pragma unroll
  for (int mb = 0; mb < 4; ++mb)
#pragma unroll
    for (int r = 0; r < 4; ++r) {
      const int row = m0 + wm + mb * 16 + ((lane >> 4) << 2) + r;
#pragma unroll
      for (int nb = 0; nb < 4; ++nb) {
        const size_t off = (size_t)row * N + n0 + wn + nb * 16 + (lane & 15);
        OutF[off] = acc[mb][nb][r] + Res[off];
      }
    }
}

// ---------------- full-row GEMM: BM=64(32 for EPI2), BN=512, BK=64, 16 waves, dbuf, LN epilogues ----------------
// EPI 0: bf16 out. 1: LN->bf16. 2: LN kv (BM=32; half0 -> k, half1 -> v transposed). 3: +Res fp32 + LN bf16.
template <int EPI>
__global__ __launch_bounds__(1024) void gemm512_kernel(
    const u16* __restrict__ A, const u16* __restrict__ W,
    const float* __restrict__ Res, float* __restrict__ OutF,
    u16* __restrict__ OutB, u16* __restrict__ OutB2,
    int K, const float* __restrict__ gam, const float* __restrict__ bet, float oscale) {
  constexpr bool RES_ = (EPI == 3);
  constexpr bool LN_ = (EPI == 1 || EPI == 2 || EPI == 3);
  constexpr int NMB = (EPI == 2) ? 1 : 2;          // 16-row strips per wave-half
  constexpr int BM = NMB * 32;
  __shared__ __align__(16) u16 As[2][BM * 64];
  __shared__ __align__(16) u16 Bs[2][512 * 64];
  const int tid = threadIdx.x;
  const int lane = tid & 63, w = tid >> 6;
  const int l15 = lane & 15, g = lane >> 4;
  int bx, by;
  if (EPI == 2) { bx = blockIdx.x >> 7; by = blockIdx.x & 127; }
  else { bx = 0; by = blockIdx.x; }
  const int m0 = by * BM;
  const int n0 = bx * 512;
  const int wm = (w >> 3) * (NMB << 4);            // 0 or NMB*16
  const int wn = (w & 7) << 6;
  const f32x4 zero = {0.f, 0.f, 0.f, 0.f};
  f32x4 acc[NMB][4];
#pragma unroll
  for (int i = 0; i < NMB; ++i)
#pragma unroll
    for (int j = 0; j < 4; ++j) acc[i][j] = zero;

  auto stage = [&](int buf, int k0) {
#pragma unroll
    for (int c = 0; c < 4; ++c) {
      const int cg = (w << 2) + c;
      const int idx = (cg << 6) + lane;
      const int row = idx >> 3, sl = idx & 7;
      const int c16 = sl ^ (row & 7);
      gload_lds16(W + (size_t)(n0 + row) * K + k0 + (c16 << 3), (char*)Bs[buf] + cg * 1024);
    }
    if (w < NMB * 4) {
      const int idx = (w << 6) + lane;
      const int row = idx >> 3, sl = idx & 7;
      const int c16 = sl ^ (row & 7);
      gload_lds16(A + (size_t)(m0 + row) * K + k0 + (c16 << 3), (char*)As[buf] + w * 1024);
    }
  };

  const int nk = K >> 6;
  stage(0, 0);
  __syncthreads();
  for (int t = 0; t < nk; ++t) {
    const int cur = t & 1;
    if (t + 1 < nk) stage(cur ^ 1, (t + 1) << 6);
#pragma unroll
    for (int kst = 0; kst < 2; ++kst) {
      const int c16 = (kst << 2) + g;
      short8 af[NMB], bfr[4];
#pragma unroll
      for (int mb = 0; mb < NMB; ++mb) af[mb] = ldsfrag(As[cur], wm + (mb << 4) + l15, c16);
#pragma unroll
      for (int nb = 0; nb < 4; ++nb) bfr[nb] = ldsfrag(Bs[cur], wn + (nb << 4) + l15, c16);
#pragma unroll
      for (int mb = 0; mb < NMB; ++mb)
#pragma unroll
        for (int nb = 0; nb < 4; ++nb)
          acc[mb][nb] = __builtin_amdgcn_mfma_f32_16x16x32_bf16(af[mb], bfr[nb], acc[mb][nb], 0, 0, 0);
    }
    __syncthreads();
  }

  if (RES_) {
#pragma unroll
    for (int mb = 0; mb < NMB; ++mb)
#pragma unroll
      for (int r = 0; r < 4; ++r) {
        const int grow = m0 + wm + (mb << 4) + (g << 2) + r;
#pragma unroll
        for (int nb = 0; nb < 4; ++nb)
          acc[mb][nb][r] += Res[(size_t)grow * kC + wn + (nb << 4) + l15];
      }
  }
  float* rs = (float*)As[0];
  float* rs2 = rs + 512;
  float2* minv = (float2*)(rs2 + 512);
  if (LN_) {
#pragma unroll
    for (int mb = 0; mb < NMB; ++mb)
#pragma unroll
      for (int r = 0; r < 4; ++r) {
        float s = acc[mb][0][r] + acc[mb][1][r] + acc[mb][2][r] + acc[mb][3][r];
        float s2 = acc[mb][0][r] * acc[mb][0][r] + acc[mb][1][r] * acc[mb][1][r] +
                   acc[mb][2][r] * acc[mb][2][r] + acc[mb][3][r] * acc[mb][3][r];
        s += __shfl_xor(s, 1); s += __shfl_xor(s, 2); s += __shfl_xor(s, 4); s += __shfl_xor(s, 8);
        s2 += __shfl_xor(s2, 1); s2 += __shfl_xor(s2, 2); s2 += __shfl_xor(s2, 4); s2 += __shfl_xor(s2, 8);
        if (l15 == 0) {
          const int rowf = wm + (mb << 4) + (g << 2) + r;
          rs[((w & 7) << 6) + rowf] = s;
          rs2[((w & 7) << 6) + rowf] = s2;
        }
      }
    __syncthreads();
    if (tid < BM) {
      float S = 0.f, SS = 0.f;
#pragma unroll
      for (int c8 = 0; c8 < 8; ++c8) { S += rs[(c8 << 6) + tid]; SS += rs2[(c8 << 6) + tid]; }
      const float mean = S * (1.0f / 512.0f);
      const float var = SS * (1.0f / 512.0f) - mean * mean;
      minv[tid] = make_float2(mean, rsqrtf(var + kEps));
    }
    __syncthreads();
  }
  float g4[4], b4[4];
  if (LN_) {
    const float* gp = (EPI == 2 && bx) ? gam + kC : gam;
    const float* bp = (EPI == 2 && bx) ? bet + kC : bet;
#pragma unroll
    for (int nb = 0; nb < 4; ++nb) {
      const int cc = wn + (nb << 4) + l15;
      g4[nb] = gp[cc];
      b4[nb] = bp[cc];
    }
  }
#pragma unroll
  for (int mb = 0; mb < NMB; ++mb) {
#pragma unroll
    for (int r = 0; r < 4; ++r) {
      const int rowf = wm + (mb << 4) + (g << 2) + r;
      const int grow = m0 + rowf;
      float2 mi = make_float2(0.f, 0.f);
      if (LN_) mi = minv[rowf];
#pragma unroll
      for (int nb = 0; nb < 4; ++nb) {
        const int cc = wn + (nb << 4) + l15;
        const float vv = acc[mb][nb][r];
        if (EPI == 0) {
          OutB[(size_t)grow * kC + cc] = f2bf(vv);
        } else if (EPI == 1) {
          OutB[(size_t)grow * kC + cc] = f2bf(((vv - mi.x) * mi.y * g4[nb] + b4[nb]) * oscale);
        } else if (EPI == 2) {
          const float lv = (vv - mi.x) * mi.y * g4[nb] + b4[nb];
          if (bx == 0) {
            OutB[(size_t)grow * kC + cc] = f2bf(lv);
          } else {
            const int b = grow >> 10, lr = grow & (kLr - 1);
            const int hh = cc >> 6, d = cc & 63;
            OutB2[((size_t)((b << 3) + hh) * 64 + d) * kLr + lr] = f2bf(lv);
          }
        } else {  // EPI 3
          OutF[(size_t)grow * kC + cc] = vv;
          OutB[(size_t)grow * kC + cc] = f2bf((vv - mi.x) * mi.y * g4[nb] + b4[nb]);
        }
      }
    }
  }
}

// ---------------- MFMA flash attention: 1024 thr (16 waves x 16 q = QBLK 256), KVBLK=128,
// Q regs, no-max exp2 softmax, in-register P, padded V (264B rows), XCD-local grid ----------------
__global__ __launch_bounds__(1024, 8) void attn_mfma_kernel(
    const u16* __restrict__ q, const u16* __restrict__ k,
    const u16* __restrict__ vt, u16* __restrict__ o) {
  __shared__ __align__(16) u16 Ks[2][128 * 64];     // 32 KB
  __shared__ __align__(16) char Vp[2][64 * 264];    // 33 KB
  const int tid = threadIdx.x;
  const int lane = tid & 63, w = tid >> 6;   // 16 waves
  const int bid = blockIdx.x;                // 512 blocks; same (b,h) -> same XCD
  const int qt = bid >> 5;                   // 0..15
  const int hb = bid & 31;
  const int h = hb >> 2, b = hb & 3;
  const int q0 = qt << 8;                    // QBLK = 256
  const int l15 = lane & 15, g = lane >> 4;

  // Q fragments in registers (B-operand of swapped QK^T), pre-scaled by 0.125*log2e in LN
  short8 qf[2];
#pragma unroll
  for (int kst = 0; kst < 2; ++kst)
    qf[kst] = *(const short8*)(q + (size_t)((b << 12) + q0 + (w << 4) + l15) * kC +
                               (h << 6) + kst * 32 + g * 8);

  // K-frag base byte offsets: full offset = kbase[kst] + nb*2048
  int kbase[2];
#pragma unroll
  for (int kst = 0; kst < 2; ++kst)
    kbase[kst] = (l15 << 7) + (((((kst << 2) + g) ^ (l15 & 7))) << 4);
  // V read offsets: addr = voff[nb] + d*4224  (d-block of 16 rows x 264B)
  int voff[8];
#pragma unroll
  for (int nb = 0; nb < 8; ++nb) {
    const int chunk = (nb << 1) + (g >> 1);               // 0..15
    const int slot = chunk ^ (l15 & 7);                   // XOR low 3 bits
    voff[nb] = l15 * 264 + (slot << 4) + ((g & 1) << 3);
  }

  // staging mapping (1024 threads)
  const int kr_ = tid >> 3;                    // 0..127 (K rows)
  const int ksl_ = tid & 7;
  const int kc16 = ksl_ ^ (kr_ & 7);
  const u16* kSrc = k + (size_t)((b << 10) + kr_) * kC + (h << 6) + (kc16 << 3);
  const int rv_ = tid >> 4;                    // 0..63 (V d-rows)
  const int jv_ = tid & 15;
  const int half_ = jv_ >> 3;                  // kv half
  const int sv_ = jv_ & 7;                     // slot within half
  const int vc16 = sv_ ^ (rv_ & 7);
  const u16* vSrc = vt + (size_t)(((b << 3) + h) * 64 + rv_) * kLr + half_ * 64 + (vc16 << 3);
  const int vdoff = rv_ * 264 + half_ * 128 + (sv_ << 4);

  auto stageK = [&](int buf) { gload_lds16(kSrc, (char*)Ks[buf] + tid * 16); };

  // stage tile 0
  stageK(0);
  kSrc += (size_t)128 * kC;
  {
    const float4 v0 = *(const float4*)vSrc;
    vSrc += 128;
    char* vd = Vp[0] + vdoff;
    *(float2*)(vd) = make_float2(v0.x, v0.y);
    *(float2*)(vd + 8) = make_float2(v0.z, v0.w);
  }

  const f32x4 zero = {0.f, 0.f, 0.f, 0.f};
  float l1 = 0.f;
  f32x4 accO[4] = {zero, zero, zero, zero};
  constexpr int nt = kLr / 128;  // 8

  __syncthreads();

  for (int t = 0; t < nt; ++t) {
    const int cur = t & 1;
    float4 vn0;
    if (t + 1 < nt) {
      vn0 = *(const float4*)vSrc;           // wait deferred to ds_write below
      vSrc += 128;
      stageK(cur ^ 1);
      kSrc += (size_t)128 * kC;
    }
    // ---- S^T = K Q^T (log2 domain), 128 kv rows ----
    const char* kb = (const char*)Ks[cur];
    f32x4 st[8];
#pragma unroll
    for (int nb = 0; nb < 8; ++nb) st[nb] = zero;
    __builtin_amdgcn_s_setprio(1);
#pragma unroll
    for (int kst = 0; kst < 2; ++kst)
#pragma unroll
      for (int nb = 0; nb < 8; ++nb) {
        const short8 ak = *(const short8*)(kb + (nb << 11) + kbase[kst]);
        st[nb] = __builtin_amdgcn_mfma_f32_16x16x32_bf16(ak, qf[kst], st[nb], 0, 0, 0);
      }
    __builtin_amdgcn_s_setprio(0);
    // ---- no-max softmax: P = exp2(S'), lane-partial l sum ----
    short4v pa[8];
    {
      float ps = 0.f;
#pragma unroll
      for (int nb = 0; nb < 8; ++nb) {
#pragma unroll
        for (int r = 0; r < 4; ++r) {
          const float e = fexp2(st[nb][r]);
          st[nb][r] = e;
          ps += e;
        }
        u32 pw[2];
        pw[0] = cvtpk(st[nb][0], st[nb][1]);
        pw[1] = cvtpk(st[nb][2], st[nb][3]);
        pa[nb] = *(short4v*)pw;
      }
      l1 += ps;
    }
    // ---- O += P V via 16x16x16 (P stays in registers) ----
    const char* vbuf = Vp[cur];
    __builtin_amdgcn_s_setprio(1);
#pragma unroll
    for (int nb = 0; nb < 8; ++nb) {
#pragma unroll
      for (int d = 0; d < 4; ++d) {
        const short4v vb = *(const short4v*)(vbuf + voff[nb] + d * 4224);
        accO[d] = MFMA16X16(pa[nb], vb, accO[d]);
      }
    }
    __builtin_amdgcn_s_setprio(0);
    // ---- write prefetched V tile (global load wait auto-inserted here) ----
    if (t + 1 < nt) {
      char* vd = Vp[cur ^ 1] + vdoff;
      *(float2*)(vd) = make_float2(vn0.x, vn0.y);
      *(float2*)(vd + 8) = make_float2(vn0.z, vn0.w);
    }
    __syncthreads();  // drains K prefetch + publishes V writes + switches buffers
  }
  // ---- final l reduction + normalize + store ----
  l1 += __shfl_xor(l1, 16);
  l1 += __shfl_xor(l1, 32);
  float li[4];
#pragma unroll
  for (int r = 0; r < 4; ++r) li[r] = 1.0f / __shfl(l1, (g << 2) + r);
  const int qg = (b << 12) + q0 + (w << 4) + (g << 2);
#pragma unroll
  for (int d = 0; d < 4; ++d)
#pragma unroll
    for (int r = 0; r < 4; ++r)
      o[(size_t)(qg + r) * kC + (h << 6) + (d << 4) + l15] = f2bf(accO[d][r] * li[r]);
}

extern "C" void kernel_launch(void* const* d_in, const int* in_sizes, int n_in,
                              void* d_out, int out_size, void* d_ws, size_t ws_size,
                              hipStream_t stream) {
  const float* x      = (const float*)d_in[0];
  const float* w_q    = (const float*)d_in[1];
  const float* w_k    = (const float*)d_in[2];
  const float* w_v    = (const float*)d_in[3];
  const float* w_o    = (const float*)d_in[4];
  const float* w_red  = (const float*)d_in[5];
  const float* w_ffn1 = (const float*)d_in[6];
  const float* w_dw   = (const float*)d_in[7];
  const float* w_ffn2 = (const float*)d_in[8];
  const float* gam    = (const float*)d_in[9];
  const float* bet    = (const float*)d_in[10];
  float* out = (float*)d_out;

  const size_t nBLC = (size_t)kB * kL * kC;    // 8,388,608
  const size_t nBLrC = (size_t)kB * kLr * kC;  // 2,097,152
  u16* us = (u16*)d_ws;
  u16* wqb   = us;                    // wq|wk|wv|wo|wf1 contiguous (wk|wv adjacent)
  u16* wkb   = wqb + 262144;
  u16* wob   = wkb + 2 * 262144;
  u16* wf1b  = wob + 262144;
  u16* wf2b  = wf1b + 262144;         // 1,048,576
  u16* wredb = wf2b + 1048576;        // 1,835,008
  u16* h_b   = wredb + 1835008;       // nBLC (h / attn-out / f1)
  u16* q_b   = h_b + nBLC;            // nBLC (q / f)  -- fdw aliases from here (67MB)
  u16* red_b = q_b + nBLC;            // nBLrC
  u16* k_b   = red_b + nBLrC;         // nBLrC
  u16* vt_b  = k_b + nBLrC;           // nBLrC
  float* S   = (float*)(vt_b + nBLrC);  // 2 x nBLrC fp32 splitK partials
  u16* fdw   = q_b;                     // B*L*CH bf16: aliases q_b|red|k|vt|S

  // merged: weight prep + LN0
  prep_ln0_kernel<<<9472 + kB * kL, 256, 0, stream>>>(
      w_q, w_k, w_v, w_o, w_ffn1, w_ffn2, wqb, w_red, wredb, x, h_b, gam, bet);
  // reducer gather-GEMM splitK=2 -> S; sum+LN1 -> red_b
  mgemm_red_kernel<<<dim3(128, 1, 2), 256, 0, stream>>>(h_b, wredb, S, kB * kLr, kC, kKred);
  reduce2_ln_kernel<<<kB * kLr, 256, 0, stream>>>(S, red_b, gam + kC, bet + kC);
  // q = LN2(h w_q^T) * (0.125 * log2 e)   (LN fused; exp2-domain attention)
  gemm512_kernel<1><<<dim3(256), 1024, 0, stream>>>(
      h_b, wqb, nullptr, nullptr, q_b, nullptr, kC, gam + 2 * kC, bet + 2 * kC,
      0.125f * 1.44269504088896f);
  // k = LN3(red w_k^T), v = LN4(red w_v^T) transposed (fused, one launch; BM=32, full fill)
  gemm512_kernel<2><<<dim3(256), 1024, 0, stream>>>(
      red_b, wkb, nullptr, nullptr, k_b, vt_b, kC, gam + 3 * kC, bet + 3 * kC, 1.0f);
  // attention -> h_b  (QBLK=256, 16 waves)
  attn_mfma_kernel<<<dim3(512), 1024, 0, stream>>>(q_b, k_b, vt_b, h_b);
  // h2 = attn w_o^T + x -> out (fp32)  AND  f = LN5(h2) -> q_b (bf16)
  gemm512_kernel<3><<<dim3(256), 1024, 0, stream>>>(
      h_b, wob, x, out, q_b, nullptr, kC, gam + 5 * kC, bet + 5 * kC, 1.0f);
  // f1 = f w_ffn1^T -> h_b (bf16)
  gemm512_kernel<0><<<dim3(256), 1024, 0, stream>>>(
      q_b, wf1b, nullptr, nullptr, h_b, nullptr, kC, nullptr, nullptr, 1.0f);
  // fdw = gelu(dw3(f1)) at full occupancy (q_b dead now)
  dwgelu_kernel<<<kB * kL, 256, 0, stream>>>(h_b, w_dw, fdw);
  // out = fdw w_ffn2^T + h2 -> out
  mgemm_res_kernel<<<dim3(512), 256, 0, stream>>>(fdw, wf2b, out, out, kB * kL, kC, kCH);
}

// Round 20
// 259.436 us; speedup vs baseline: 1.4705x; 1.4705x over previous
//
#include <hip/hip_runtime.h>
#include <math.h>

typedef __attribute__((ext_vector_type(8))) short short8;
typedef __attribute__((ext_vector_type(4))) short short4v;
typedef __attribute__((ext_vector_type(4))) float f32x4;
typedef unsigned short u16;
typedef unsigned int u32;
typedef unsigned long long u64;

namespace {
constexpr int kB = 4;
constexpr int kL = 4096;
constexpr int kC = 512;
constexpr int kH = 8;
constexpr int kLr = 1024;
constexpr int kCH = 2048;
constexpr int kKred = 3584;
constexpr float kEps = 1e-5f;
}

#if __has_builtin(__builtin_amdgcn_mfma_f32_16x16x16bf16_1k)
#define MFMA16X16(a, b, c) __builtin_amdgcn_mfma_f32_16x16x16bf16_1k((a), (b), (c), 0, 0, 0)
#else
__device__ __forceinline__ f32x4 mfma16_fb(short4v a, short4v b, f32x4 c) {
  asm volatile("v_mfma_f32_16x16x16_bf16 %0, %1, %2, %0\n\ts_nop 7\n\ts_nop 3"
               : "+v"(c) : "v"(a), "v"(b));
  return c;
}
#define MFMA16X16(a, b, c) mfma16_fb((a), (b), (c))
#endif

__device__ __forceinline__ float bf2f(u16 u) { return __uint_as_float(((u32)u) << 16); }
__device__ __forceinline__ u16 f2bf(float f) {
  u32 u = __float_as_uint(f);
  u32 r = (u + 0x7fffu + ((u >> 16) & 1u)) >> 16;
  return (u16)r;
}
__device__ __forceinline__ u32 cvtpk(float lo, float hi) {
  u32 r;
  asm("v_cvt_pk_bf16_f32 %0, %1, %2" : "=v"(r) : "v"(lo), "v"(hi));
  return r;
}
__device__ __forceinline__ float fexp2(float x) {
#if __has_builtin(__builtin_amdgcn_exp2f)
  return __builtin_amdgcn_exp2f(x);
#else
  float r;
  asm("v_exp_f32 %0, %1" : "=v"(r) : "v"(x));
  return r;
#endif
}

__device__ __forceinline__ void gload_lds16(const void* g, void* l) {
  __builtin_amdgcn_global_load_lds(
      (const __attribute__((address_space(1))) unsigned int*)g,
      (__attribute__((address_space(3))) unsigned int*)l, 16, 0, 0);
}

// swizzled frag read: rows of 64 bf16 (128B), XOR (row&7) on 16B slot index
__device__ __forceinline__ short8 ldsfrag(const u16* base, int row, int col16) {
  return *(const short8*)(base + (size_t)(((row << 3) + (col16 ^ (row & 7))) << 3));
}

// ---------------- merged prologue: weight cvt/repack + LN0 ----------------
__global__ __launch_bounds__(256) void prep_ln0_kernel(
    const float* __restrict__ w_q, const float* __restrict__ w_k,
    const float* __restrict__ w_v, const float* __restrict__ w_o,
    const float* __restrict__ w_f1, const float* __restrict__ w_f2,
    u16* __restrict__ dst, const float* __restrict__ w_red, u16* __restrict__ wredb,
    const float* __restrict__ x, u16* __restrict__ h_out,
    const float* __restrict__ gam, const float* __restrict__ bet) {
  const int bid = blockIdx.x;
  const int tid = threadIdx.x;
  if (bid < 2304) {
    const int i = (bid * 256 + tid) * 4;  // total 2,359,296
    const int seg = i >> 18;
    const float* src;
    int off;
    if (seg < 5) {
      src = (seg == 0) ? w_q : (seg == 1) ? w_k : (seg == 2) ? w_v : (seg == 3) ? w_o : w_f1;
      off = i & 262143;
    } else {
      src = w_f2;
      off = i - 1310720;
    }
    const float4 v = *(const float4*)(src + off);
    u16 o[4] = {f2bf(v.x), f2bf(v.y), f2bf(v.z), f2bf(v.w)};
    *(u64*)(dst + i) = *(u64*)o;
    return;
  }
  if (bid < 9472) {
    const int idx = (bid - 2304) * 256 + tid;
    if (idx >= kC * kKred) return;
    const int o = idx / kKred;
    const int rem = idx - o * kKred;
    const int t = rem >> 9;
    const int i = rem & (kC - 1);
    wredb[idx] = f2bf(w_red[(size_t)(o * kC + i) * 7 + t]);
    return;
  }
  // ---- LN0 over row = bid - 9472 ----
  const int row = bid - 9472;
  const float2 v = *(const float2*)(x + (size_t)row * kC + tid * 2);
  float s = v.x + v.y;
  float ss = v.x * v.x + v.y * v.y;
#pragma unroll
  for (int off = 32; off > 0; off >>= 1) {
    s += __shfl_down(s, off);
    ss += __shfl_down(ss, off);
  }
  __shared__ float wsum[4][2];
  __shared__ float mi[2];
  const int wave = tid >> 6, lane = tid & 63;
  if (lane == 0) { wsum[wave][0] = s; wsum[wave][1] = ss; }
  __syncthreads();
  if (tid == 0) {
    const float S = wsum[0][0] + wsum[1][0] + wsum[2][0] + wsum[3][0];
    const float SS = wsum[0][1] + wsum[1][1] + wsum[2][1] + wsum[3][1];
    const float mean = S * (1.0f / kC);
    const float var = SS * (1.0f / kC) - mean * mean;
    mi[0] = mean;
    mi[1] = rsqrtf(var + kEps);
  }
  __syncthreads();
  const float mean = mi[0], inv = mi[1];
  const float2 gg = *(const float2*)(gam + tid * 2);
  const float2 bb = *(const float2*)(bet + tid * 2);
  u16 o2[2] = {f2bf((v.x - mean) * inv * gg.x + bb.x), f2bf((v.y - mean) * inv * gg.y + bb.y)};
  *(u32*)(h_out + (size_t)row * kC + tid * 2) = *(u32*)o2;
}

// ---------------- sum 2 split-K fp32 partials -> LN -> bf16 ----------------
__global__ __launch_bounds__(256) void reduce2_ln_kernel(const float* __restrict__ P,
                                                         u16* __restrict__ out,
                                                         const float* __restrict__ g,
                                                         const float* __restrict__ be) {
  const int row = blockIdx.x;
  const int tid = threadIdx.x;
  const size_t stride = (size_t)kB * kLr * kC;
  float2 v = make_float2(0.f, 0.f);
#pragma unroll
  for (int z = 0; z < 2; ++z) {
    const float2 p = *(const float2*)(P + z * stride + (size_t)row * kC + tid * 2);
    v.x += p.x;
    v.y += p.y;
  }
  float s = v.x + v.y;
  float ss = v.x * v.x + v.y * v.y;
#pragma unroll
  for (int off = 32; off > 0; off >>= 1) {
    s += __shfl_down(s, off);
    ss += __shfl_down(ss, off);
  }
  __shared__ float wsum[4][2];
  __shared__ float mi[2];
  const int wave = tid >> 6, lane = tid & 63;
  if (lane == 0) { wsum[wave][0] = s; wsum[wave][1] = ss; }
  __syncthreads();
  if (tid == 0) {
    const float S = wsum[0][0] + wsum[1][0] + wsum[2][0] + wsum[3][0];
    const float SS = wsum[0][1] + wsum[1][1] + wsum[2][1] + wsum[3][1];
    const float mean = S * (1.0f / kC);
    const float var = SS * (1.0f / kC) - mean * mean;
    mi[0] = mean;
    mi[1] = rsqrtf(var + kEps);
  }
  __syncthreads();
  const float mean = mi[0], inv = mi[1];
  const float2 gg = *(const float2*)(g + tid * 2);
  const float2 bb = *(const float2*)(be + tid * 2);
  u16 o2[2] = {f2bf((v.x - mean) * inv * gg.x + bb.x), f2bf((v.y - mean) * inv * gg.y + bb.y)};
  *(u32*)(out + (size_t)row * kC + tid * 2) = *(u32*)o2;
}

// ---------------- fdw = gelu(dwconv3(f1)); full occupancy elementwise ----------------
__global__ __launch_bounds__(256) void dwgelu_kernel(const u16* __restrict__ f1,
                                                     const float* __restrict__ wdw,
                                                     u16* __restrict__ fdw) {
  const int row = blockIdx.x;
  const int l = row & (kL - 1);
  const int rb = row - l;
  const int cc0 = threadIdx.x * 8;
  const int cg = cc0 >> 2;
  const int lm = (l == 0) ? 1 : l - 1;
  const int lp = (l == kL - 1) ? kL - 2 : l + 1;
  const u32 xm = *(const u32*)(f1 + (size_t)(rb + lm) * kC + cg);
  const u32 x0 = *(const u32*)(f1 + (size_t)(rb + l) * kC + cg);
  const u32 xp = *(const u32*)(f1 + (size_t)(rb + lp) * kC + cg);
  const float xml = bf2f((u16)xm), xmh = bf2f((u16)(xm >> 16));
  const float x0l = bf2f((u16)x0), x0h = bf2f((u16)(x0 >> 16));
  const float xpl = bf2f((u16)xp), xph = bf2f((u16)(xp >> 16));
  float wv[24];
#pragma unroll
  for (int t = 0; t < 6; ++t)
    *(float4*)&wv[t * 4] = *(const float4*)(wdw + (size_t)cc0 * 3 + t * 4);
  short8 pk;
#pragma unroll
  for (int j = 0; j < 8; ++j) {
    const float a_ = (j < 4) ? xml : xmh;
    const float b_ = (j < 4) ? x0l : x0h;
    const float c_ = (j < 4) ? xpl : xph;
    const float dw = wv[j * 3] * a_ + wv[j * 3 + 1] * b_ + wv[j * 3 + 2] * c_;
    pk[j] = (short)f2bf(0.5f * dw * (1.0f + erff(dw * 0.70710678118654752440f)));
  }
  *(short8*)(fdw + (size_t)row * kCH + cc0) = pk;
}

// ---------------- MFMA bf16 GEMM (128x128, splitK, dbuf, 4 waves) for reducer ----------------
__global__ __launch_bounds__(256) void mgemm_red_kernel(
    const u16* __restrict__ A, const u16* __restrict__ W, float* __restrict__ OutF,
    int M, int N, int K) {
  __shared__ __align__(16) u16 As[2][128 * 64];
  __shared__ __align__(16) u16 Bs[2][128 * 64];
  const int tid = threadIdx.x;
  const int lane = tid & 63, w = tid >> 6;
  const int bid = blockIdx.x;
  const int m0 = (bid & 31) << 7, n0 = (bid >> 5) << 7;
  const int wm = (w >> 1) * 64, wn = (w & 1) * 64;
  const f32x4 zero = {0.f, 0.f, 0.f, 0.f};
  f32x4 acc[4][4];
#pragma unroll
  for (int i = 0; i < 4; ++i)
#pragma unroll
    for (int j = 0; j < 4; ++j) acc[i][j] = zero;

  const int kc = K / gridDim.z;
  const int kBeg = blockIdx.z * kc;
  float* outp = OutF + (size_t)blockIdx.z * M * N;

  auto stage = [&](int buf, int k0) {
#pragma unroll
    for (int c = 0; c < 4; ++c) {
      const int ci = w * 4 + c;
      const int idx = ci * 64 + lane;
      const int row = idx >> 3, s = idx & 7;
      const int c16 = s ^ (row & 7);
      gload_lds16(W + (size_t)(n0 + row) * K + k0 + c16 * 8, (char*)Bs[buf] + ci * 1024);
      const int m = m0 + row;
      const int b = m >> 10, lr = m & (kLr - 1);
      const int k = k0 + c16 * 8;
      const int t = k >> 9, i = k & (kC - 1);
      int pos = 4 * lr + t - 3;
      pos = pos < 0 ? -pos : (pos >= kL ? 2 * kL - 2 - pos : pos);
      gload_lds16(A + ((size_t)(b << 12) + pos) * kC + i, (char*)As[buf] + ci * 1024);
    }
  };

  const int nk = kc >> 6;
  stage(0, kBeg);
  __syncthreads();
  for (int t = 0; t < nk; ++t) {
    const int cur = t & 1;
    if (t + 1 < nk) stage(cur ^ 1, kBeg + ((t + 1) << 6));
#pragma unroll
    for (int kst = 0; kst < 2; ++kst) {
      short8 af[4], bfr[4];
      const int c16 = kst * 4 + (lane >> 4);
#pragma unroll
      for (int mb = 0; mb < 4; ++mb) af[mb] = ldsfrag(As[cur], wm + mb * 16 + (lane & 15), c16);
#pragma unroll
      for (int nb = 0; nb < 4; ++nb) bfr[nb] = ldsfrag(Bs[cur], wn + nb * 16 + (lane & 15), c16);
#pragma unroll
      for (int mb = 0; mb < 4; ++mb)
#pragma unroll
        for (int nb = 0; nb < 4; ++nb)
          acc[mb][nb] = __builtin_amdgcn_mfma_f32_16x16x32_bf16(af[mb], bfr[nb], acc[mb][nb], 0, 0, 0);
    }
    __syncthreads();
  }
#pragma unroll
  for (int mb = 0; mb < 4; ++mb)
#pragma unroll
    for (int r = 0; r < 4; ++r) {
      const int row = m0 + wm + mb * 16 + ((lane >> 4) << 2) + r;
#pragma unroll
      for (int nb = 0; nb < 4; ++nb)
        outp[(size_t)row * N + n0 + wn + nb * 16 + (lane & 15)] = acc[mb][nb][r];
    }
}

// ---------------- MFMA bf16 GEMM (128x128, dbuf, 4 waves) + fp32 residual (ffn2) ----------------
__global__ __launch_bounds__(256) void mgemm_res_kernel(
    const u16* __restrict__ A, const u16* __restrict__ W,
    const float* __restrict__ Res, float* __restrict__ OutF, int M, int N, int K) {
  __shared__ __align__(16) u16 As[2][128 * 64];
  __shared__ __align__(16) u16 Bs[2][128 * 64];
  const int tid = threadIdx.x;
  const int lane = tid & 63, w = tid >> 6;
  const int bid = blockIdx.x;
  const int m0 = (bid & 127) << 7, n0 = (bid >> 7) << 7;
  const int wm = (w >> 1) * 64, wn = (w & 1) * 64;
  const f32x4 zero = {0.f, 0.f, 0.f, 0.f};
  f32x4 acc[4][4];
#pragma unroll
  for (int i = 0; i < 4; ++i)
#pragma unroll
    for (int j = 0; j < 4; ++j) acc[i][j] = zero;

  auto stage = [&](int buf, int k0) {
#pragma unroll
    for (int c = 0; c < 4; ++c) {
      const int ci = w * 4 + c;
      const int idx = ci * 64 + lane;
      const int row = idx >> 3, s = idx & 7;
      const int c16 = s ^ (row & 7);
      gload_lds16(W + (size_t)(n0 + row) * K + k0 + c16 * 8, (char*)Bs[buf] + ci * 1024);
      gload_lds16(A + (size_t)(m0 + row) * K + k0 + c16 * 8, (char*)As[buf] + ci * 1024);
    }
  };

  const int nk = K >> 6;
  stage(0, 0);
  __syncthreads();
  for (int t = 0; t < nk; ++t) {
    const int cur = t & 1;
    if (t + 1 < nk) stage(cur ^ 1, (t + 1) << 6);
#pragma unroll
    for (int kst = 0; kst < 2; ++kst) {
      short8 af[4], bfr[4];
      const int c16 = kst * 4 + (lane >> 4);
#pragma unroll
      for (int mb = 0; mb < 4; ++mb) af[mb] = ldsfrag(As[cur], wm + mb * 16 + (lane & 15), c16);
#pragma unroll
      for (int nb = 0; nb < 4; ++nb) bfr[nb] = ldsfrag(Bs[cur], wn + nb * 16 + (lane & 15), c16);
#pragma unroll
      for (int mb = 0; mb < 4; ++mb)
#pragma unroll
        for (int nb = 0; nb < 4; ++nb)
          acc[mb][nb] = __builtin_amdgcn_mfma_f32_16x16x32_bf16(af[mb], bfr[nb], acc[mb][nb], 0, 0, 0);
    }
    __syncthreads();
  }
#pragma unroll
  for (int mb = 0; mb < 4; ++mb)
#pragma unroll
    for (int r = 0; r < 4; ++r) {
      const int row = m0 + wm + mb * 16 + ((lane >> 4) << 2) + r;
#pragma unroll
      for (int nb = 0; nb < 4; ++nb) {
        const size_t off = (size_t)row * N + n0 + wn + nb * 16 + (lane & 15);
        OutF[off] = acc[mb][nb][r] + Res[off];
      }
    }
}

// ---------------- full-row GEMM: BM=64(32 for EPI2), BN=512, BK=64, 16 waves, dbuf, LN epilogues ----------------
// EPI 0: bf16 out. 1: LN->bf16. 2: LN kv (BM=32; half0 -> k, half1 -> v transposed). 3: +Res fp32 + LN bf16.
template <int EPI>
__global__ __launch_bounds__(1024) void gemm512_kernel(
    const u16* __restrict__ A, const u16* __restrict__ W,
    const float* __restrict__ Res, float* __restrict__ OutF,
    u16* __restrict__ OutB, u16* __restrict__ OutB2,
    int K, const float* __restrict__ gam, const float* __restrict__ bet, float oscale) {
  constexpr bool RES_ = (EPI == 3);
  constexpr bool LN_ = (EPI == 1 || EPI == 2 || EPI == 3);
  constexpr int NMB = (EPI == 2) ? 1 : 2;          // 16-row strips per wave-half
  constexpr int BM = NMB * 32;
  __shared__ __align__(16) u16 As[2][BM * 64];
  __shared__ __align__(16) u16 Bs[2][512 * 64];
  const int tid = threadIdx.x;
  const int lane = tid & 63, w = tid >> 6;
  const int l15 = lane & 15, g = lane >> 4;
  int bx, by;
  if (EPI == 2) { bx = blockIdx.x >> 7; by = blockIdx.x & 127; }
  else { bx = 0; by = blockIdx.x; }
  const int m0 = by * BM;
  const int n0 = bx * 512;
  const int wm = (w >> 3) * (NMB << 4);            // 0 or NMB*16
  const int wn = (w & 7) << 6;
  const f32x4 zero = {0.f, 0.f, 0.f, 0.f};
  f32x4 acc[NMB][4];
#pragma unroll
  for (int i = 0; i < NMB; ++i)
#pragma unroll
    for (int j = 0; j < 4; ++j) acc[i][j] = zero;

  auto stage = [&](int buf, int k0) {
#pragma unroll
    for (int c = 0; c < 4; ++c) {
      const int cg = (w << 2) + c;
      const int idx = (cg << 6) + lane;
      const int row = idx >> 3, sl = idx & 7;
      const int c16 = sl ^ (row & 7);
      gload_lds16(W + (size_t)(n0 + row) * K + k0 + (c16 << 3), (char*)Bs[buf] + cg * 1024);
    }
    if (w < NMB * 4) {
      const int idx = (w << 6) + lane;
      const int row = idx >> 3, sl = idx & 7;
      const int c16 = sl ^ (row & 7);
      gload_lds16(A + (size_t)(m0 + row) * K + k0 + (c16 << 3), (char*)As[buf] + w * 1024);
    }
  };

  const int nk = K >> 6;
  stage(0, 0);
  __syncthreads();
  for (int t = 0; t < nk; ++t) {
    const int cur = t & 1;
    if (t + 1 < nk) stage(cur ^ 1, (t + 1) << 6);
#pragma unroll
    for (int kst = 0; kst < 2; ++kst) {
      const int c16 = (kst << 2) + g;
      short8 af[NMB], bfr[4];
#pragma unroll
      for (int mb = 0; mb < NMB; ++mb) af[mb] = ldsfrag(As[cur], wm + (mb << 4) + l15, c16);
#pragma unroll
      for (int nb = 0; nb < 4; ++nb) bfr[nb] = ldsfrag(Bs[cur], wn + (nb << 4) + l15, c16);
#pragma unroll
      for (int mb = 0; mb < NMB; ++mb)
#pragma unroll
        for (int nb = 0; nb < 4; ++nb)
          acc[mb][nb] = __builtin_amdgcn_mfma_f32_16x16x32_bf16(af[mb], bfr[nb], acc[mb][nb], 0, 0, 0);
    }
    __syncthreads();
  }

  if (RES_) {
#pragma unroll
    for (int mb = 0; mb < NMB; ++mb)
#pragma unroll
      for (int r = 0; r < 4; ++r) {
        const int grow = m0 + wm + (mb << 4) + (g << 2) + r;
#pragma unroll
        for (int nb = 0; nb < 4; ++nb)
          acc[mb][nb][r] += Res[(size_t)grow * kC + wn + (nb << 4) + l15];
      }
  }
  float* rs = (float*)As[0];
  float* rs2 = rs + 512;
  float2* minv = (float2*)(rs2 + 512);
  if (LN_) {
#pragma unroll
    for (int mb = 0; mb < NMB; ++mb)
#pragma unroll
      for (int r = 0; r < 4; ++r) {
        float s = acc[mb][0][r] + acc[mb][1][r] + acc[mb][2][r] + acc[mb][3][r];
        float s2 = acc[mb][0][r] * acc[mb][0][r] + acc[mb][1][r] * acc[mb][1][r] +
                   acc[mb][2][r] * acc[mb][2][r] + acc[mb][3][r] * acc[mb][3][r];
        s += __shfl_xor(s, 1); s += __shfl_xor(s, 2); s += __shfl_xor(s, 4); s += __shfl_xor(s, 8);
        s2 += __shfl_xor(s2, 1); s2 += __shfl_xor(s2, 2); s2 += __shfl_xor(s2, 4); s2 += __shfl_xor(s2, 8);
        if (l15 == 0) {
          const int rowf = wm + (mb << 4) + (g << 2) + r;
          rs[((w & 7) << 6) + rowf] = s;
          rs2[((w & 7) << 6) + rowf] = s2;
        }
      }
    __syncthreads();
    if (tid < BM) {
      float S = 0.f, SS = 0.f;
#pragma unroll
      for (int c8 = 0; c8 < 8; ++c8) { S += rs[(c8 << 6) + tid]; SS += rs2[(c8 << 6) + tid]; }
      const float mean = S * (1.0f / 512.0f);
      const float var = SS * (1.0f / 512.0f) - mean * mean;
      minv[tid] = make_float2(mean, rsqrtf(var + kEps));
    }
    __syncthreads();
  }
  float g4[4], b4[4];
  if (LN_) {
    const float* gp = (EPI == 2 && bx) ? gam + kC : gam;
    const float* bp = (EPI == 2 && bx) ? bet + kC : bet;
#pragma unroll
    for (int nb = 0; nb < 4; ++nb) {
      const int cc = wn + (nb << 4) + l15;
      g4[nb] = gp[cc];
      b4[nb] = bp[cc];
    }
  }
#pragma unroll
  for (int mb = 0; mb < NMB; ++mb) {
#pragma unroll
    for (int r = 0; r < 4; ++r) {
      const int rowf = wm + (mb << 4) + (g << 2) + r;
      const int grow = m0 + rowf;
      float2 mi = make_float2(0.f, 0.f);
      if (LN_) mi = minv[rowf];
#pragma unroll
      for (int nb = 0; nb < 4; ++nb) {
        const int cc = wn + (nb << 4) + l15;
        const float vv = acc[mb][nb][r];
        if (EPI == 0) {
          OutB[(size_t)grow * kC + cc] = f2bf(vv);
        } else if (EPI == 1) {
          OutB[(size_t)grow * kC + cc] = f2bf(((vv - mi.x) * mi.y * g4[nb] + b4[nb]) * oscale);
        } else if (EPI == 2) {
          const float lv = (vv - mi.x) * mi.y * g4[nb] + b4[nb];
          if (bx == 0) {
            OutB[(size_t)grow * kC + cc] = f2bf(lv);
          } else {
            const int b = grow >> 10, lr = grow & (kLr - 1);
            const int hh = cc >> 6, d = cc & 63;
            OutB2[((size_t)((b << 3) + hh) * 64 + d) * kLr + lr] = f2bf(lv);
          }
        } else {  // EPI 3
          OutF[(size_t)grow * kC + cc] = vv;
          OutB[(size_t)grow * kC + cc] = f2bf((vv - mi.x) * mi.y * g4[nb] + b4[nb]);
        }
      }
    }
  }
}

// ---------------- MFMA flash attention: 512 thr, QBLK=128, KVBLK=128 (8 tiles), Q regs,
// no-max exp2 softmax, in-register P, padded V (264B rows), XCD-local grid ----------------
__global__ __launch_bounds__(512, 4) void attn_mfma_kernel(
    const u16* __restrict__ q, const u16* __restrict__ k,
    const u16* __restrict__ vt, u16* __restrict__ o) {
  __shared__ __align__(16) u16 Ks[2][128 * 64];     // 32 KB
  __shared__ __align__(16) char Vp[2][64 * 264];    // 33 KB: 64 d-rows x (256B kv + 8B pad)
  const int tid = threadIdx.x;
  const int lane = tid & 63, w = tid >> 6;   // 8 waves
  const int bid = blockIdx.x;                // same (b,h) -> same XCD
  const int qt = bid >> 5;
  const int hb = bid & 31;
  const int h = hb >> 2, b = hb & 3;
  const int q0 = qt << 7;                    // QBLK = 128
  const int l15 = lane & 15, g = lane >> 4;

  // Q fragments in registers (B-operand of swapped QK^T), pre-scaled by 0.125*log2e in LN
  short8 qf[2];
#pragma unroll
  for (int kst = 0; kst < 2; ++kst)
    qf[kst] = *(const short8*)(q + (size_t)((b << 12) + q0 + (w << 4) + l15) * kC +
                               (h << 6) + kst * 32 + g * 8);

  // K-frag base byte offsets: full offset = kbase[kst] + nb*2048
  int kbase[2];
#pragma unroll
  for (int kst = 0; kst < 2; ++kst)
    kbase[kst] = (l15 << 7) + (((((kst << 2) + g) ^ (l15 & 7))) << 4);
  // V read offsets: addr = voff[nb] + d*4224  (d-block of 16 rows x 264B)
  int voff[8];
#pragma unroll
  for (int nb = 0; nb < 8; ++nb) {
    const int chunk = (nb << 1) + (g >> 1);               // 0..15
    const int slot = chunk ^ (l15 & 7);                   // XOR low 3 bits
    voff[nb] = l15 * 264 + (slot << 4) + ((g & 1) << 3);
  }

  // staging mapping
  const int r_ = tid >> 3;                     // 0..63
  const int sl_ = tid & 7;
  const int c16 = sl_ ^ (r_ & 7);
  const u16* kSrc = k + (size_t)((b << 10) + r_) * kC + (h << 6) + (c16 << 3);
  const u16* vSrc = vt + (size_t)(((b << 3) + h) * 64 + r_) * kLr + (c16 << 3);
  const int vdoff = r_ * 264 + (sl_ << 4);     // slots sl_ and sl_+8 (at +128)

  auto stageK = [&](int buf) {
    gload_lds16(kSrc, (char*)Ks[buf] + tid * 16);
    gload_lds16(kSrc + (size_t)64 * kC, (char*)Ks[buf] + 8192 + tid * 16);
  };

  // stage tile 0
  stageK(0);
  kSrc += (size_t)128 * kC;
  {
    const float4 v0 = *(const float4*)vSrc;
    const float4 v1 = *(const float4*)(vSrc + 64);
    vSrc += 128;
    char* vd = Vp[0] + vdoff;
    *(float2*)(vd) = make_float2(v0.x, v0.y);
    *(float2*)(vd + 8) = make_float2(v0.z, v0.w);
    *(float2*)(vd + 128) = make_float2(v1.x, v1.y);
    *(float2*)(vd + 136) = make_float2(v1.z, v1.w);
  }

  const f32x4 zero = {0.f, 0.f, 0.f, 0.f};
  float l1 = 0.f;
  f32x4 accO[4] = {zero, zero, zero, zero};
  constexpr int nt = kLr / 128;  // 8

  __syncthreads();

  for (int t = 0; t < nt; ++t) {
    const int cur = t & 1;
    float4 vn0, vn1;
    if (t + 1 < nt) {
      vn0 = *(const float4*)vSrc;           // waits deferred to ds_write below
      vn1 = *(const float4*)(vSrc + 64);
      vSrc += 128;
      stageK(cur ^ 1);
      kSrc += (size_t)128 * kC;
    }
    // ---- S^T = K Q^T (log2 domain), 128 kv rows ----
    const char* kb = (const char*)Ks[cur];
    f32x4 st[8];
#pragma unroll
    for (int nb = 0; nb < 8; ++nb) st[nb] = zero;
    __builtin_amdgcn_s_setprio(1);
#pragma unroll
    for (int kst = 0; kst < 2; ++kst)
#pragma unroll
      for (int nb = 0; nb < 8; ++nb) {
        const short8 ak = *(const short8*)(kb + (nb << 11) + kbase[kst]);
        st[nb] = __builtin_amdgcn_mfma_f32_16x16x32_bf16(ak, qf[kst], st[nb], 0, 0, 0);
      }
    __builtin_amdgcn_s_setprio(0);
    // ---- no-max softmax: P = exp2(S'), lane-partial l sum ----
    short4v pa[8];
    {
      float ps = 0.f;
#pragma unroll
      for (int nb = 0; nb < 8; ++nb) {
#pragma unroll
        for (int r = 0; r < 4; ++r) {
          const float e = fexp2(st[nb][r]);
          st[nb][r] = e;
          ps += e;
        }
        u32 pw[2];
        pw[0] = cvtpk(st[nb][0], st[nb][1]);
        pw[1] = cvtpk(st[nb][2], st[nb][3]);
        pa[nb] = *(short4v*)pw;
      }
      l1 += ps;
    }
    // ---- O += P V via 16x16x16 (P stays in registers) ----
    const char* vbuf = Vp[cur];
    __builtin_amdgcn_s_setprio(1);
#pragma unroll
    for (int nb = 0; nb < 8; ++nb) {
#pragma unroll
      for (int d = 0; d < 4; ++d) {
        const short4v vb = *(const short4v*)(vbuf + voff[nb] + d * 4224);
        accO[d] = MFMA16X16(pa[nb], vb, accO[d]);
      }
    }
    __builtin_amdgcn_s_setprio(0);
    // ---- write prefetched V tile (global load wait auto-inserted here) ----
    if (t + 1 < nt) {
      char* vd = Vp[cur ^ 1] + vdoff;
      *(float2*)(vd) = make_float2(vn0.x, vn0.y);
      *(float2*)(vd + 8) = make_float2(vn0.z, vn0.w);
      *(float2*)(vd + 128) = make_float2(vn1.x, vn1.y);
      *(float2*)(vd + 136) = make_float2(vn1.z, vn1.w);
    }
    __syncthreads();  // drains K prefetch + publishes V writes + switches buffers
  }
  // ---- final l reduction + normalize + store ----
  l1 += __shfl_xor(l1, 16);
  l1 += __shfl_xor(l1, 32);
  float li[4];
#pragma unroll
  for (int r = 0; r < 4; ++r) li[r] = 1.0f / __shfl(l1, (g << 2) + r);
  const int qg = (b << 12) + q0 + (w << 4) + (g << 2);
#pragma unroll
  for (int d = 0; d < 4; ++d)
#pragma unroll
    for (int r = 0; r < 4; ++r)
      o[(size_t)(qg + r) * kC + (h << 6) + (d << 4) + l15] = f2bf(accO[d][r] * li[r]);
}

extern "C" void kernel_launch(void* const* d_in, const int* in_sizes, int n_in,
                              void* d_out, int out_size, void* d_ws, size_t ws_size,
                              hipStream_t stream) {
  const float* x      = (const float*)d_in[0];
  const float* w_q    = (const float*)d_in[1];
  const float* w_k    = (const float*)d_in[2];
  const float* w_v    = (const float*)d_in[3];
  const float* w_o    = (const float*)d_in[4];
  const float* w_red  = (const float*)d_in[5];
  const float* w_ffn1 = (const float*)d_in[6];
  const float* w_dw   = (const float*)d_in[7];
  const float* w_ffn2 = (const float*)d_in[8];
  const float* gam    = (const float*)d_in[9];
  const float* bet    = (const float*)d_in[10];
  float* out = (float*)d_out;

  const size_t nBLC = (size_t)kB * kL * kC;    // 8,388,608
  const size_t nBLrC = (size_t)kB * kLr * kC;  // 2,097,152
  u16* us = (u16*)d_ws;
  u16* wqb   = us;                    // wq|wk|wv|wo|wf1 contiguous (wk|wv adjacent)
  u16* wkb   = wqb + 262144;
  u16* wob   = wkb + 2 * 262144;
  u16* wf1b  = wob + 262144;
  u16* wf2b  = wf1b + 262144;         // 1,048,576
  u16* wredb = wf2b + 1048576;        // 1,835,008
  u16* h_b   = wredb + 1835008;       // nBLC (h / attn-out / f1)
  u16* q_b   = h_b + nBLC;            // nBLC (q / f)  -- fdw aliases from here (67MB)
  u16* red_b = q_b + nBLC;            // nBLrC
  u16* k_b   = red_b + nBLrC;         // nBLrC
  u16* vt_b  = k_b + nBLrC;           // nBLrC
  float* S   = (float*)(vt_b + nBLrC);  // 2 x nBLrC fp32 splitK partials
  u16* fdw   = q_b;                     // B*L*CH bf16: aliases q_b|red|k|vt|S

  // merged: weight prep + LN0
  prep_ln0_kernel<<<9472 + kB * kL, 256, 0, stream>>>(
      w_q, w_k, w_v, w_o, w_ffn1, w_ffn2, wqb, w_red, wredb, x, h_b, gam, bet);
  // reducer gather-GEMM splitK=2 -> S; sum+LN1 -> red_b
  mgemm_red_kernel<<<dim3(128, 1, 2), 256, 0, stream>>>(h_b, wredb, S, kB * kLr, kC, kKred);
  reduce2_ln_kernel<<<kB * kLr, 256, 0, stream>>>(S, red_b, gam + kC, bet + kC);
  // q = LN2(h w_q^T) * (0.125 * log2 e)   (LN fused; exp2-domain attention)
  gemm512_kernel<1><<<dim3(256), 1024, 0, stream>>>(
      h_b, wqb, nullptr, nullptr, q_b, nullptr, kC, gam + 2 * kC, bet + 2 * kC,
      0.125f * 1.44269504088896f);
  // k = LN3(red w_k^T), v = LN4(red w_v^T) transposed (fused, one launch; BM=32, full fill)
  gemm512_kernel<2><<<dim3(256), 1024, 0, stream>>>(
      red_b, wkb, nullptr, nullptr, k_b, vt_b, kC, gam + 3 * kC, bet + 3 * kC, 1.0f);
  // attention -> h_b  (512 thr, QBLK=128)
  attn_mfma_kernel<<<dim3(1024), 512, 0, stream>>>(q_b, k_b, vt_b, h_b);
  // h2 = attn w_o^T + x -> out (fp32)  AND  f = LN5(h2) -> q_b (bf16)
  gemm512_kernel<3><<<dim3(256), 1024, 0, stream>>>(
      h_b, wob, x, out, q_b, nullptr, kC, gam + 5 * kC, bet + 5 * kC, 1.0f);
  // f1 = f w_ffn1^T -> h_b (bf16)
  gemm512_kernel<0><<<dim3(256), 1024, 0, stream>>>(
      q_b, wf1b, nullptr, nullptr, h_b, nullptr, kC, nullptr, nullptr, 1.0f);
  // fdw = gelu(dw3(f1)) at full occupancy (q_b dead now)
  dwgelu_kernel<<<kB * kL, 256, 0, stream>>>(h_b, w_dw, fdw);
  // out = fdw w_ffn2^T + h2 -> out
  mgemm_res_kernel<<<dim3(512), 256, 0, stream>>>(fdw, wf2b, out, out, kB * kL, kC, kCH);
}